// Round 16
// baseline (668.159 us; speedup 1.0000x reference)
//
#include <hip/hip_runtime.h>

typedef unsigned short ushort_t;
typedef _Float16 half8 __attribute__((ext_vector_type(8)));
typedef float f32x4 __attribute__((ext_vector_type(4)));

constexpr int NN  = 30000;
constexpr int EE  = 480000;
constexpr int NEXM = 64;
constexpr int CATOMS = 10000;           // atoms per chunk (3 chunks)
constexpr int ATB = 8;                  // dst atoms owned per mega_pass block
constexpr int WCAP_TILES = 10600;       // W chunk buffer capacity (tiles)

#define MFMA16(a,b,c) __builtin_amdgcn_mfma_f32_16x16x32_f16((a),(b),(c),0,0,0)
#define LDS_ADD(p,v) __hip_atomic_fetch_add((p),(v),__ATOMIC_RELAXED,__HIP_MEMORY_SCOPE_WORKGROUP)
#define LGKM_WAIT asm volatile("s_waitcnt lgkmcnt(0)" ::: "memory")

__device__ __forceinline__ float fast_tanh(float x){
  float e2 = __builtin_amdgcn_exp2f(x * 2.885390081777927f);
  return 1.f - 2.f * __builtin_amdgcn_rcpf(e2 + 1.f);
}
__device__ __forceinline__ ushort_t f2h(float v){
  union { _Float16 h; ushort_t s; } cv; cv.h = (_Float16)v; return cv.s;
}

// ---------------- weight pre-swizzle into MFMA fragment order -----------------
// ushort offsets: w1T(A) 0 | w2T(A) 24576 | l2T(A) 73728 | blkT(A) 122880 |
//                 l1T(A) 172032 | ow1T(A) 221184 | total 229376
__global__ __launch_bounds__(256) void prep_weights(
  const float* __restrict__ fw1, const float* __restrict__ fb1,
  const float* __restrict__ fw2, const float* __restrict__ l1w,
  const float* __restrict__ l2w, const float* __restrict__ bw,
  const float* __restrict__ ow1, ushort_t* __restrict__ frags)
{
  int u = blockIdx.x*256 + threadIdx.x;
  float val;
  if (u < 24576){                       // w1T A-frags, K padded 50->64, row50=bias
    int b = u >> 13; int v = u & 8191;
    int j = v & 7, lane = (v>>3)&63, fid = v>>9;     // fid = mt*2+ks
    int mt = fid>>1, ks = fid&1;
    int f1 = mt*16 + (lane&15);
    int k  = ks*32 + ((lane>>4)&3)*8 + j;
    val = (k < 50) ? fw1[(b*50 + k)*128 + f1] : (k == 50 ? fb1[b*128 + f1] : 0.f);
  } else if (u < 73728){                // w2T A-frags (A[m=f2][k=f1]), fid = mt*4+ks
    int v = u - 24576; int b = v >> 14; int v2 = v & 16383;
    int j = v2&7, lane = (v2>>3)&63, fid = v2>>9;
    int mt = fid>>2, ks = fid&3;
    int n = mt*16 + (lane&15);          // f2
    int k = ks*32 + ((lane>>4)&3)*8 + j; // f1
    val = fw2[b*16384 + k*128 + n];
  } else if (u < 221184){               // l2T / blkT / l1T A-frags, fid = mt*4+ks
    int v = u - 73728; int g = v / 49152; int v1 = v - g*49152;
    int b = v1 >> 14; int v2 = v1 & 16383;
    int j = v2&7, lane=(v2>>3)&63, fid=v2>>9;
    int mt = fid>>2, ks = fid&3;
    int n = mt*16 + (lane&15);
    int k = ks*32 + ((lane>>4)&3)*8 + j;
    const float* W = (g==0? l2w : (g==1? bw : l1w));
    val = W[b*16384 + k*128 + n];
  } else {                              // ow1T A-frags [128x64], fid = mt*4+ks
    int v2 = u - 221184;
    int j = v2&7, lane=(v2>>3)&63, fid=v2>>9;
    int mt = fid>>2, ks = fid&3;
    int n = mt*16 + (lane&15);
    int k = ks*32 + ((lane>>4)&3)*8 + j;
    val = ow1[k*64 + n];
  }
  frags[u] = f2h(val);
}

// ---------------- dst-sort: histogram -> scan -> fused scatter+meta -----------
__global__ __launch_bounds__(256) void count_k(
  const int* __restrict__ ei, int* __restrict__ cnt)
{
  int e = blockIdx.x*256 + threadIdx.x;
  atomicAdd(cnt + ei[EE + e], 1);
}

__global__ __launch_bounds__(1024) void scan_k(
  const int* __restrict__ cnt, int* __restrict__ off)
{
  __shared__ int wsum[16];
  __shared__ int carry;
  int tid = threadIdx.x, lane = tid&63, w = tid>>6;
  if (tid==0) carry = 0;
  __syncthreads();
  for (int base=0; base<NN; base+=1024){
    int i = base + tid;
    int v = (i<NN) ? cnt[i] : 0;
    int s = v;
    #pragma unroll
    for (int o=1;o<64;o<<=1){ int t = __shfl_up(s,o,64); if (lane>=o) s += t; }
    if (lane==63) wsum[w] = s;
    __syncthreads();
    if (tid < 16){
      int t = wsum[tid];
      #pragma unroll
      for (int o=1;o<16;o<<=1){ int u2 = __shfl_up(t,o,16); if (tid>=o) t += u2; }
      wsum[tid] = t;
    }
    __syncthreads();
    int wbase = (w==0) ? 0 : wsum[w-1];
    if (i<NN) off[i] = carry + wbase + s - v;
    __syncthreads();
    if (tid==0) carry += wsum[15];
    __syncthreads();
  }
}

// fused scatter + edge geometry: writes dst-sorted meta rows directly.
// after this, off[d] == end of segment d (exclusive).
__global__ __launch_bounds__(256) void scatter_meta(
  const float* __restrict__ pos, const int* __restrict__ ei,
  int* __restrict__ off, uint4* __restrict__ meta)
{
  int e = blockIdx.x*256 + threadIdx.x;
  int s = ei[e], d = ei[EE + e];
  float dx = pos[s*3+0]-pos[d*3+0];
  float dy = pos[s*3+1]-pos[d*3+1];
  float dz = pos[s*3+2]-pos[d*3+2];
  float dist = sqrtf(dx*dx+dy*dy+dz*dz + 1e-12f);
  float c = 0.5f*(cosf(dist*0.31415926535897931f)+1.f);
  c = (dist < 10.f) ? c : 0.f;
  int p = atomicAdd(off + d, 1);
  uint4 m;
  m.x = __float_as_uint(dist);
  m.y = __float_as_uint(c);
  m.z = (unsigned)s;
  m.w = (unsigned)d;
  meta[p] = m;
}

// ---------------- fused embedding gather + h0 = x @ lin1[0] -------------------
__global__ __launch_bounds__(256) void embed_h0(
  const int* __restrict__ atype, const float* __restrict__ emb,
  const ushort_t* __restrict__ l1T, float* __restrict__ x, ushort_t* __restrict__ h)
{
  __shared__ float xbuf[4*2112];        // 33.8 KB, per-wave 2112 floats
  const int wave = threadIdx.x>>6, lane = threadIdx.x&63;
  const int quad = lane>>4, n15 = lane&15;
  float* xw = xbuf + wave*2112;
  ushort_t* sw = (ushort_t*)xw;
  const half8* wv = (const half8*)l1T;
  const f32x4 zero4 = {0.f,0.f,0.f,0.f};
  const int ntiles = NN/16;
  const int stride = gridDim.x*4;
  for (int tile = blockIdx.x*4 + wave; tile < ntiles; tile += stride){
    int a0 = tile*16;
    int typ = atype[a0 + n15];
    const f32x4* av = (const f32x4*)(emb + (size_t)typ*128);
    half8 bg[4]; f32x4 xl[4], xh[4];
    #pragma unroll
    for (int ks=0;ks<4;ks++){
      f32x4 lo = av[ks*8 + quad*2];
      f32x4 hi = av[ks*8 + quad*2 + 1];
      xl[ks] = lo; xh[ks] = hi;
      half8 bh;
      #pragma unroll
      for (int i=0;i<4;i++){ bh[i]=(_Float16)lo[i]; bh[4+i]=(_Float16)hi[i]; }
      bg[ks] = bh;
    }
    f32x4 acc[8];
    #pragma unroll
    for (int mt=0;mt<8;mt++) acc[mt] = zero4;
    #pragma unroll
    for (int ks=0;ks<4;ks++){
      #pragma unroll
      for (int mt=0;mt<8;mt++) acc[mt] = MFMA16(wv[(mt*4+ks)*64 + lane], bg[ks], acc[mt]);
    }
    #pragma unroll
    for (int ks=0;ks<4;ks++){
      *(f32x4*)(xw + n15*132 + ks*32 + quad*8)     = xl[ks];
      *(f32x4*)(xw + n15*132 + ks*32 + quad*8 + 4) = xh[ks];
    }
    LGKM_WAIT;
    {
      float* gx = x + (size_t)a0*128;
      #pragma unroll
      for (int it=0;it<8;it++){
        int off = it*256 + lane*4;
        f32x4 v = *(const f32x4*)(xw + (off>>7)*132 + (off&127));
        *(f32x4*)(gx + off) = v;
      }
    }
    LGKM_WAIT;
    #pragma unroll
    for (int mt=0;mt<8;mt++){
      union { ushort_t s[4]; uint2 v; } pk;
      #pragma unroll
      for (int r=0;r<4;r++) pk.s[r] = f2h(acc[mt][r]);
      *(uint2*)(sw + n15*132 + mt*16 + quad*4) = pk.v;
    }
    LGKM_WAIT;
    {
      ushort_t* gh = h + (size_t)a0*128;
      #pragma unroll
      for (int it=0;it<4;it++){
        int off = it*512 + lane*8;
        uint4 v = *(const uint4*)(sw + (off>>7)*132 + (off&127));
        *(uint4*)(gh + off) = v;
      }
    }
    LGKM_WAIT;
  }
}

// ---------------- mega message pass + fused node update -----------------------
// r15 structure (proven 52us) at finer granularity: ATB=8 (~128 edges, ~8-11
// tiles). Same LDS (49.7KB -> 3 blocks/CU), same registers ((256,3), a1 in
// VGPRs, ldsW2 staged). Phase 2: 32 threads/atom (even/odd split + shfl).
// 1250 blocks/chunk -> finer packing, shorter stragglers.
__global__ __launch_bounds__(256,3) void mega_pass(
  const uint4* __restrict__ meta, const ushort_t* __restrict__ hin,
  ushort_t* __restrict__ hout,
  const ushort_t* __restrict__ w1g, const ushort_t* __restrict__ w2g,
  const float* __restrict__ b2,
  const ushort_t* __restrict__ l2T, const ushort_t* __restrict__ bkT,
  const ushort_t* __restrict__ l1Tn,
  const float* __restrict__ l2b, const float* __restrict__ bb,
  const int* __restrict__ segend, int first_atom,
  ushort_t* __restrict__ W, float* __restrict__ x, int do_h)
{
  __shared__ ushort_t ldsW2[16384];     // 32 KB: w2T A-frags
  __shared__ ushort_t st[4*2112];       // 16.5 KB: per-wave transpose buffers
  ushort_t* nt = st;                    // node tile aliases wave-0 region
  const int wave = threadIdx.x>>6, lane = threadIdx.x&63;
  const int quad = lane>>4, n15 = lane&15;
  {
    const uint4* s2 = (const uint4*)w2g; uint4* d2 = (uint4*)ldsW2;
    #pragma unroll
    for (int i=0;i<8;i++) d2[threadIdx.x + i*256] = s2[threadIdx.x + i*256];
  }
  half8 a1[16];
  const half8* w1v = (const half8*)w1g;
  #pragma unroll
  for (int i=0;i<16;i++) a1[i] = w1v[i*64 + lane];
  f32x4 b2v[8];
  #pragma unroll
  for (int mt=0;mt<8;mt++) b2v[mt] = *(const f32x4*)(b2 + mt*16 + quad*4);

  const int base  = first_atom + blockIdx.x*ATB;
  const int elo   = (base==0) ? 0 : segend[base-1];
  const int ehi   = segend[base + ATB - 1];
  const int elo_c = (first_atom==0) ? 0 : segend[first_atom-1];
  __syncthreads();

  const half8* w2l = (const half8*)ldsW2;
  ushort_t* tw = st + wave*2112;
  const f32x4 zero4 = {0.f,0.f,0.f,0.f};
  const float dd = 10.f/49.f;
  const float coefl2 = (-0.5f/(dd*dd)) * 1.4426950408889634f;

  // ---- phase 1: compute W for this block's tiles ----
  const int tlo = elo >> 4, thi = (ehi + 15) >> 4;
  for (int tile = tlo + wave; tile < thi; tile += 4){
    const int e0 = tile*16;
    uint2 dc = *(const uint2*)(meta + e0 + n15);
    float de = __uint_as_float(dc.x);
    float Cv = __uint_as_float(dc.y);
    half8 rb0, rb1;
    #pragma unroll
    for (int j=0;j<8;j++){
      int k0 = quad*8 + j;
      float t0 = de - (float)k0*dd;
      rb0[j] = (_Float16)__builtin_amdgcn_exp2f(coefl2*t0*t0);
      int k1 = 32 + quad*8 + j;
      float v1;
      if (k1 < 50){ float t1 = de - (float)k1*dd; v1 = __builtin_amdgcn_exp2f(coefl2*t1*t1); }
      else v1 = (k1 == 50) ? 1.f : 0.f;
      rb1[j] = (_Float16)v1;
    }
    // GEMM1: D[m=f1][n=e]
    f32x4 acc1[8];
    #pragma unroll
    for (int mt=0;mt<8;mt++){
      acc1[mt] = MFMA16(a1[mt*2],   rb0, zero4);
      acc1[mt] = MFMA16(a1[mt*2+1], rb1, acc1[mt]);
    }
    #pragma unroll
    for (int mt=0;mt<8;mt++){
      union { ushort_t s[4]; uint2 v; } pk;
      #pragma unroll
      for (int r=0;r<4;r++) pk.s[r] = f2h(fast_tanh(acc1[mt][r]));
      *(uint2*)(tw + n15*132 + mt*16 + quad*4) = pk.v;
    }
    LGKM_WAIT;
    // GEMM2: A = w2T frags (LDS), B = t (LDS): D[m=f2][n=e]
    f32x4 acc2[8];
    #pragma unroll
    for (int mt=0;mt<8;mt++) acc2[mt] = zero4;
    #pragma unroll
    for (int ks=0;ks<4;ks++){
      const ushort_t* ra = tw + n15*132 + ks*32 + quad*8;
      union { uint2 v[2]; half8 h16; } cc;
      cc.v[0] = *(const uint2*)(ra);
      cc.v[1] = *(const uint2*)(ra + 4);
      half8 tb = cc.h16;
      #pragma unroll
      for (int mt=0;mt<8;mt++) acc2[mt] = MFMA16(w2l[(mt*4+ks)*64 + lane], tb, acc2[mt]);
    }
    LGKM_WAIT;
    #pragma unroll
    for (int mt=0;mt<8;mt++){
      f32x4 v = acc2[mt] + b2v[mt];
      union { ushort_t s[4]; uint2 q; } pk;
      #pragma unroll
      for (int r=0;r<4;r++) pk.s[r] = f2h(v[r] * Cv);
      *(uint2*)(tw + n15*132 + mt*16 + quad*4) = pk.q;
    }
    LGKM_WAIT;
    #pragma unroll
    for (int it=0;it<4;it++){
      int off = it*512 + lane*8;
      int erow = e0 + (off>>7);
      if (erow >= elo_c){
        uint4 v = *(const uint4*)(tw + (off>>7)*132 + (off&127));
        *(uint4*)(W + (size_t)(erow - elo_c)*128 + (off&127)) = v;
      }
    }
  }
  __threadfence_block();
  __syncthreads();

  // ---- phase 2: gather-multiply-reduce (32 threads/atom) -> fp16 agg tile ----
  {
    const int atomL = wave*2 + (lane>>5);      // 0..7
    const int sub   = (lane>>4)&1;
    const int tf    = lane&15;
    const int a  = base + atomL;
    const int lo = (a==0) ? 0 : segend[a-1];
    const int hi = segend[a];
    float acc[8];
    #pragma unroll
    for (int j=0;j<8;j++) acc[j] = 0.f;
    const int* msrc = (const int*)meta;
    int e = lo + sub;
    if (e < hi){
      int src = msrc[(size_t)e*4 + 2];
      half8 wv = *(const half8*)(W + (size_t)(e - elo_c)*128 + tf*8);
      half8 hv = *(const half8*)(hin + (size_t)src*128 + tf*8);
      while (true){
        int en = e + 2;
        bool more = en < hi;
        half8 wv2 = wv, hv2 = hv;
        if (more){
          int sn = msrc[(size_t)en*4 + 2];
          wv2 = *(const half8*)(W + (size_t)(en - elo_c)*128 + tf*8);
          hv2 = *(const half8*)(hin + (size_t)sn*128 + tf*8);
        }
        #pragma unroll
        for (int j=0;j<8;j++) acc[j] += (float)wv[j] * (float)hv[j];
        if (!more) break;
        wv = wv2; hv = hv2; e = en;
      }
    }
    // combine even/odd partials: lanes 0-15 += lanes 16-31 (ditto 32-47/48-63)
    #pragma unroll
    for (int j=0;j<8;j++){
      float o = __shfl_down(acc[j], 16);
      acc[j] += o;
    }
    if (sub == 0){
      union { ushort_t s[8]; uint4 q; } pk;
      #pragma unroll
      for (int j=0;j<8;j++) pk.s[j] = f2h(acc[j]);
      *(uint4*)(nt + atomL*132 + tf*8) = pk.q;
    }
  }
  __syncthreads();

  // ---- phase 3: node update for this block's 8-atom tile ----
  {
    // B-frags of agg tile: lane n15 = atom (rows >= ATB are garbage, masked)
    half8 bg[4];
    #pragma unroll
    for (int ks=0;ks<4;ks++){
      const ushort_t* ra = nt + n15*132 + ks*32 + quad*8;
      union { uint2 v[2]; half8 h16; } cc;
      cc.v[0] = *(const uint2*)(ra);
      cc.v[1] = *(const uint2*)(ra + 4);
      bg[ks] = cc.h16;
    }
    __syncthreads();                     // reads done before t overwrites nt
    const half8* wAv = (const half8*)l2T;
    f32x4 accA[2];
    #pragma unroll
    for (int i=0;i<2;i++) accA[i] = zero4;
    #pragma unroll
    for (int ks=0;ks<4;ks++){
      #pragma unroll
      for (int i=0;i<2;i++)
        accA[i] = MFMA16(wAv[((wave*2+i)*4+ks)*64 + lane], bg[ks], accA[i]);
    }
    #pragma unroll
    for (int i=0;i<2;i++){
      int mt = wave*2 + i;
      f32x4 bv = *(const f32x4*)(l2b + mt*16 + quad*4);
      union { ushort_t s[4]; uint2 v; } pk;
      #pragma unroll
      for (int r=0;r<4;r++) pk.s[r] = f2h(fast_tanh(accA[i][r] + bv[r]));
      *(uint2*)(nt + n15*132 + mt*16 + quad*4) = pk.v;
    }
    __syncthreads();
    half8 bg2[4];
    #pragma unroll
    for (int ks=0;ks<4;ks++){
      const ushort_t* ra = nt + n15*132 + ks*32 + quad*8;
      union { uint2 v[2]; half8 h16; } cc;
      cc.v[0] = *(const uint2*)(ra);
      cc.v[1] = *(const uint2*)(ra + 4);
      bg2[ks] = cc.h16;
    }
    __syncthreads();                     // reads done before xn overwrites nt
    const half8* wBv = (const half8*)bkT;
    f32x4 accB[2];
    #pragma unroll
    for (int i=0;i<2;i++) accB[i] = zero4;
    #pragma unroll
    for (int ks=0;ks<4;ks++){
      #pragma unroll
      for (int i=0;i<2;i++)
        accB[i] = MFMA16(wBv[((wave*2+i)*4+ks)*64 + lane], bg2[ks], accB[i]);
    }
    f32x4 xn[2];
    float* xp = x + (size_t)(base + n15)*128;
    #pragma unroll
    for (int i=0;i<2;i++){
      int mt = wave*2 + i;
      f32x4 bv = *(const f32x4*)(bb + mt*16 + quad*4);
      f32x4 xv = *(const f32x4*)(xp + mt*16 + quad*4);
      xn[i] = xv + accB[i] + bv;
      if (n15 < ATB) *(f32x4*)(xp + mt*16 + quad*4) = xn[i];
    }
    if (do_h){
      #pragma unroll
      for (int i=0;i<2;i++){
        int mt = wave*2 + i;
        union { ushort_t s[4]; uint2 v; } pk;
        #pragma unroll
        for (int r=0;r<4;r++) pk.s[r] = f2h(xn[i][r]);
        *(uint2*)(nt + n15*132 + mt*16 + quad*4) = pk.v;
      }
      __syncthreads();
      half8 bg3[4];
      #pragma unroll
      for (int ks=0;ks<4;ks++){
        const ushort_t* ra = nt + n15*132 + ks*32 + quad*8;
        union { uint2 v[2]; half8 h16; } cc;
        cc.v[0] = *(const uint2*)(ra);
        cc.v[1] = *(const uint2*)(ra + 4);
        bg3[ks] = cc.h16;
      }
      const half8* wCv = (const half8*)l1Tn;
      f32x4 accC[2];
      #pragma unroll
      for (int i=0;i<2;i++) accC[i] = zero4;
      #pragma unroll
      for (int ks=0;ks<4;ks++){
        #pragma unroll
        for (int i=0;i<2;i++)
          accC[i] = MFMA16(wCv[((wave*2+i)*4+ks)*64 + lane], bg3[ks], accC[i]);
      }
      if (n15 < ATB){
        ushort_t* hp = hout + (size_t)(base + n15)*128;
        #pragma unroll
        for (int i=0;i<2;i++){
          int mt = wave*2 + i;
          union { ushort_t s[4]; uint2 v; } pk;
          #pragma unroll
          for (int r=0;r<4;r++) pk.s[r] = f2h(accC[i][r]);
          *(uint2*)(hp + mt*16 + quad*4) = pk.v;
        }
      }
    }
  }
}

// ---------------- fused output head: tanh(x@ow1+b1)@ow2 + ob2, per-mol sum ----
__global__ __launch_bounds__(256) void out_head(
  const float* __restrict__ x, const ushort_t* __restrict__ o1T,
  const float* __restrict__ ob1, const float* __restrict__ ow2,
  const float* __restrict__ ob2, const int* __restrict__ batch,
  float* __restrict__ out)
{
  __shared__ float part[NEXM];
  const int tid = threadIdx.x;
  if (tid < NEXM) part[tid] = 0.f;
  __syncthreads();
  const int wave = tid>>6, lane = tid&63;
  const int quad = lane>>4, n15 = lane&15;
  const half8* wv = (const half8*)o1T;
  const f32x4 zero4 = {0.f,0.f,0.f,0.f};
  f32x4 ow2v[4], ob1v[4];
  #pragma unroll
  for (int mt=0;mt<4;mt++){
    ow2v[mt] = *(const f32x4*)(ow2 + mt*16 + quad*4);
    ob1v[mt] = *(const f32x4*)(ob1 + mt*16 + quad*4);
  }
  const float ob2v = ob2[0];
  const int ntiles = NN/16;
  const int stride = gridDim.x*4;
  for (int tile = blockIdx.x*4 + wave; tile < ntiles; tile += stride){
    int a0 = tile*16;
    half8 bg[4];
    const f32x4* av = (const f32x4*)(x + (size_t)(a0 + n15)*128);
    #pragma unroll
    for (int ks=0;ks<4;ks++){
      f32x4 lo = av[ks*8 + quad*2];
      f32x4 hi = av[ks*8 + quad*2 + 1];
      half8 bh;
      #pragma unroll
      for (int i=0;i<4;i++){ bh[i]=(_Float16)lo[i]; bh[4+i]=(_Float16)hi[i]; }
      bg[ks] = bh;
    }
    f32x4 acc[4];
    #pragma unroll
    for (int mt=0;mt<4;mt++) acc[mt] = zero4;
    #pragma unroll
    for (int ks=0;ks<4;ks++){
      #pragma unroll
      for (int mt=0;mt<4;mt++) acc[mt] = MFMA16(wv[(mt*4+ks)*64 + lane], bg[ks], acc[mt]);
    }
    float e = 0.f;
    #pragma unroll
    for (int mt=0;mt<4;mt++){
      f32x4 v = acc[mt] + ob1v[mt];
      #pragma unroll
      for (int r=0;r<4;r++) e += fast_tanh(v[r]) * ow2v[mt][r];
    }
    e += __shfl_xor(e, 16, 64);
    e += __shfl_xor(e, 32, 64);
    if (quad == 0){
      int a = a0 + n15;
      LDS_ADD(&part[batch[a]], e + ob2v);
    }
  }
  __syncthreads();
  if (tid < NEXM)
    __hip_atomic_fetch_add(out + tid, part[tid], __ATOMIC_RELAXED, __HIP_MEMORY_SCOPE_AGENT);
}

// ---------------- host orchestration ------------------------------------------
extern "C" void kernel_launch(void* const* d_in, const int* in_sizes, int n_in,
                              void* d_out, int out_size, void* d_ws, size_t ws_size,
                              hipStream_t stream)
{
  const float* pos  = (const float*)d_in[0];
  const int*   atyp = (const int*)  d_in[1];
  const int*   ei   = (const int*)  d_in[2];
  const int*   bat  = (const int*)  d_in[3];
  const float* emb  = (const float*)d_in[4];
  const float* fw1  = (const float*)d_in[5];
  const float* fb1  = (const float*)d_in[6];
  const float* fw2  = (const float*)d_in[7];
  const float* fb2  = (const float*)d_in[8];
  const float* l1w  = (const float*)d_in[9];
  const float* l2w  = (const float*)d_in[10];
  const float* l2b  = (const float*)d_in[11];
  const float* bw   = (const float*)d_in[12];
  const float* bb   = (const float*)d_in[13];
  const float* ow1  = (const float*)d_in[14];
  const float* ob1  = (const float*)d_in[15];
  const float* ow2  = (const float*)d_in[16];
  const float* ob2  = (const float*)d_in[17];
  float* out = (float*)d_out;

  char* p = (char*)d_ws;
  uint4*    meta = (uint4*)p;    p += (size_t)EE*16;     //  7.68 MB {d,C,src,dst}
  ushort_t* hA   = (ushort_t*)p; p += (size_t)NN*128*2;  //  7.68 MB
  ushort_t* hB   = (ushort_t*)p; p += (size_t)NN*128*2;  //  7.68 MB
  float*    x    = (float*)p;    p += (size_t)NN*128*4;  // 15.36 MB
  ushort_t* frags = (ushort_t*)p; p += 229376*2;         //  0.46 MB
  int*      segend = (int*)p;    p += (size_t)NN*4;      //  0.12 MB
  ushort_t* Wbuf = (ushort_t*)p; p += (size_t)WCAP_TILES*2048*2; // 43.4 MB => ~82.4 MB

  // aliased scratch: cnt lives in x (dead before embed_h0 writes x)
  int* cnt = (int*)x;

  ushort_t* w1T = frags;                 // 3 x 8192
  ushort_t* w2T = frags + 24576;         // 3 x 16384 (A-frags of w2^T)
  ushort_t* l2T = frags + 73728;         // 3 x 16384
  ushort_t* bkT = frags + 122880;        // 3 x 16384
  ushort_t* l1T = frags + 172032;        // 3 x 16384
  ushort_t* o1T = frags + 221184;        // 8192

  hipMemsetAsync(d_out, 0, NEXM*sizeof(float), stream);
  hipMemsetAsync(cnt, 0, NN*sizeof(int), stream);
  prep_weights<<<896,256,0,stream>>>(fw1,fb1,fw2,l1w,l2w,bw,ow1,frags);
  count_k<<<EE/256,256,0,stream>>>(ei, cnt);
  scan_k<<<1,1024,0,stream>>>(cnt, segend);
  scatter_meta<<<EE/256,256,0,stream>>>(pos, ei, segend, meta); // segend -> ends
  embed_h0<<<512,256,0,stream>>>(atyp, emb, l1T, x, hA);        // x + h0 fused

  const int MBLK = CATOMS / ATB;   // 1250 blocks per chunk
  for (int b=0;b<3;b++){
    const ushort_t* hin = (b & 1) ? hB : hA;
    ushort_t*       hoB = (b & 1) ? hA : hB;
    int do_h = (b < 2) ? 1 : 0;
    for (int c=0;c<3;c++){
      mega_pass<<<MBLK,256,0,stream>>>(meta, hin, hoB,
                                       w1T + b*8192, w2T + b*16384, fb2 + b*128,
                                       l2T + b*16384, bkT + b*16384,
                                       l1T + ((b<2)?(b+1):0)*16384,
                                       l2b + b*128, bb + b*128,
                                       segend, c*CATOMS, Wbuf, x, do_h);
    }
  }
  out_head<<<256,256,0,stream>>>(x, o1T, ob1, ow2, ob2, bat, out);
}

// Round 17
// 585.355 us; speedup vs baseline: 1.1415x; 1.1415x over previous
//
#include <hip/hip_runtime.h>

typedef unsigned short ushort_t;
typedef _Float16 half8 __attribute__((ext_vector_type(8)));
typedef float f32x4 __attribute__((ext_vector_type(4)));

constexpr int NN  = 30000;
constexpr int EE  = 480000;
constexpr int NEXM = 64;
constexpr int CATOMS = 10000;           // atoms per chunk (3 chunks)
constexpr int ATB = 16;                 // dst atoms owned per mega_pass block
constexpr int WCAP_TILES = 10600;       // W chunk buffer capacity (tiles)
constexpr int NSB = (NN + 255) / 256;   // scan blocks (118)

#define MFMA16(a,b,c) __builtin_amdgcn_mfma_f32_16x16x32_f16((a),(b),(c),0,0,0)
#define LDS_ADD(p,v) __hip_atomic_fetch_add((p),(v),__ATOMIC_RELAXED,__HIP_MEMORY_SCOPE_WORKGROUP)
#define LGKM_WAIT asm volatile("s_waitcnt lgkmcnt(0)" ::: "memory")

__device__ __forceinline__ float fast_tanh(float x){
  float e2 = __builtin_amdgcn_exp2f(x * 2.885390081777927f);
  return 1.f - 2.f * __builtin_amdgcn_rcpf(e2 + 1.f);
}
__device__ __forceinline__ ushort_t f2h(float v){
  union { _Float16 h; ushort_t s; } cv; cv.h = (_Float16)v; return cv.s;
}

// ---------------- weight pre-swizzle into MFMA fragment order -----------------
// ushort offsets: w1T(A) 0 | w2T(A) 24576 | l2T(A) 73728 | blkT(A) 122880 |
//                 l1T(A) 172032 | ow1T(A) 221184 | total 229376
__global__ __launch_bounds__(256) void prep_weights(
  const float* __restrict__ fw1, const float* __restrict__ fb1,
  const float* __restrict__ fw2, const float* __restrict__ l1w,
  const float* __restrict__ l2w, const float* __restrict__ bw,
  const float* __restrict__ ow1, ushort_t* __restrict__ frags)
{
  int u = blockIdx.x*256 + threadIdx.x;
  float val;
  if (u < 24576){                       // w1T A-frags, K padded 50->64, row50=bias
    int b = u >> 13; int v = u & 8191;
    int j = v & 7, lane = (v>>3)&63, fid = v>>9;     // fid = mt*2+ks
    int mt = fid>>1, ks = fid&1;
    int f1 = mt*16 + (lane&15);
    int k  = ks*32 + ((lane>>4)&3)*8 + j;
    val = (k < 50) ? fw1[(b*50 + k)*128 + f1] : (k == 50 ? fb1[b*128 + f1] : 0.f);
  } else if (u < 73728){                // w2T A-frags (A[m=f2][k=f1]), fid = mt*4+ks
    int v = u - 24576; int b = v >> 14; int v2 = v & 16383;
    int j = v2&7, lane = (v2>>3)&63, fid = v2>>9;
    int mt = fid>>2, ks = fid&3;
    int n = mt*16 + (lane&15);          // f2
    int k = ks*32 + ((lane>>4)&3)*8 + j; // f1
    val = fw2[b*16384 + k*128 + n];
  } else if (u < 221184){               // l2T / blkT / l1T A-frags, fid = mt*4+ks
    int v = u - 73728; int g = v / 49152; int v1 = v - g*49152;
    int b = v1 >> 14; int v2 = v1 & 16383;
    int j = v2&7, lane=(v2>>3)&63, fid=v2>>9;
    int mt = fid>>2, ks = fid&3;
    int n = mt*16 + (lane&15);
    int k = ks*32 + ((lane>>4)&3)*8 + j;
    const float* W = (g==0? l2w : (g==1? bw : l1w));
    val = W[b*16384 + k*128 + n];
  } else {                              // ow1T A-frags [128x64], fid = mt*4+ks
    int v2 = u - 221184;
    int j = v2&7, lane=(v2>>3)&63, fid=v2>>9;
    int mt = fid>>2, ks = fid&3;
    int n = mt*16 + (lane&15);
    int k = ks*32 + ((lane>>4)&3)*8 + j;
    val = ow1[k*64 + n];
  }
  frags[u] = f2h(val);
}

// ---------------- dst-sort: histogram -> 3-stage parallel scan ----------------
__global__ __launch_bounds__(256) void count_k(
  const int* __restrict__ ei, int* __restrict__ cnt)
{
  int e = blockIdx.x*256 + threadIdx.x;
  atomicAdd(cnt + ei[EE + e], 1);
}

// stage 1: per-block (256 atoms) EXCLUSIVE scan + block total
__global__ __launch_bounds__(256) void scan1(
  const int* __restrict__ cnt, int* __restrict__ seg, int* __restrict__ bsum)
{
  __shared__ int ws[4];
  int i = blockIdx.x*256 + threadIdx.x;
  int lane = threadIdx.x & 63, w = threadIdx.x >> 6;
  int v = (i < NN) ? cnt[i] : 0;
  int s = v;
  #pragma unroll
  for (int o=1;o<64;o<<=1){ int t = __shfl_up(s,o,64); if (lane>=o) s += t; }
  if (lane == 63) ws[w] = s;
  __syncthreads();
  int add = 0;
  #pragma unroll
  for (int j=0;j<3;j++) if (w > j) add += ws[j];
  s += add;
  if (i < NN) seg[i] = s - v;          // exclusive prefix within block
  if (threadIdx.x == 255) bsum[blockIdx.x] = s;  // block total
}

// stage 2: one block scans the 118 block totals -> exclusive offsets (in place)
__global__ __launch_bounds__(128) void scan2(int* __restrict__ bsum)
{
  __shared__ int w0tot;
  int tid = threadIdx.x, lane = tid & 63, w = tid >> 6;
  int v = (tid < NSB) ? bsum[tid] : 0;
  int s = v;
  #pragma unroll
  for (int o=1;o<64;o<<=1){ int t = __shfl_up(s,o,64); if (lane>=o) s += t; }
  if (w == 0 && lane == 63) w0tot = s;
  __syncthreads();
  if (w == 1) s += w0tot;
  if (tid < NSB) bsum[tid] = s - v;    // exclusive
}

// stage 3: add block offsets -> global exclusive prefix (segment starts)
__global__ __launch_bounds__(256) void scan3(
  int* __restrict__ seg, const int* __restrict__ bsum)
{
  int i = blockIdx.x*256 + threadIdx.x;
  if (i < NN) seg[i] += bsum[blockIdx.x];
}

// fused scatter + edge geometry: writes dst-sorted meta rows directly.
// after this, seg[d] == end of segment d (exclusive).
__global__ __launch_bounds__(256) void scatter_meta(
  const float* __restrict__ pos, const int* __restrict__ ei,
  int* __restrict__ off, uint4* __restrict__ meta)
{
  int e = blockIdx.x*256 + threadIdx.x;
  int s = ei[e], d = ei[EE + e];
  float dx = pos[s*3+0]-pos[d*3+0];
  float dy = pos[s*3+1]-pos[d*3+1];
  float dz = pos[s*3+2]-pos[d*3+2];
  float dist = sqrtf(dx*dx+dy*dy+dz*dz + 1e-12f);
  float c = 0.5f*(cosf(dist*0.31415926535897931f)+1.f);
  c = (dist < 10.f) ? c : 0.f;
  int p = atomicAdd(off + d, 1);
  uint4 m;
  m.x = __float_as_uint(dist);
  m.y = __float_as_uint(c);
  m.z = (unsigned)s;
  m.w = (unsigned)d;
  meta[p] = m;
}

// ---------------- fused embedding gather + h0 = x @ lin1[0] -------------------
__global__ __launch_bounds__(256) void embed_h0(
  const int* __restrict__ atype, const float* __restrict__ emb,
  const ushort_t* __restrict__ l1T, float* __restrict__ x, ushort_t* __restrict__ h)
{
  __shared__ float xbuf[4*2112];        // 33.8 KB, per-wave 2112 floats
  const int wave = threadIdx.x>>6, lane = threadIdx.x&63;
  const int quad = lane>>4, n15 = lane&15;
  float* xw = xbuf + wave*2112;
  ushort_t* sw = (ushort_t*)xw;
  const half8* wv = (const half8*)l1T;
  const f32x4 zero4 = {0.f,0.f,0.f,0.f};
  const int ntiles = NN/16;
  const int stride = gridDim.x*4;
  for (int tile = blockIdx.x*4 + wave; tile < ntiles; tile += stride){
    int a0 = tile*16;
    int typ = atype[a0 + n15];
    const f32x4* av = (const f32x4*)(emb + (size_t)typ*128);
    half8 bg[4]; f32x4 xl[4], xh[4];
    #pragma unroll
    for (int ks=0;ks<4;ks++){
      f32x4 lo = av[ks*8 + quad*2];
      f32x4 hi = av[ks*8 + quad*2 + 1];
      xl[ks] = lo; xh[ks] = hi;
      half8 bh;
      #pragma unroll
      for (int i=0;i<4;i++){ bh[i]=(_Float16)lo[i]; bh[4+i]=(_Float16)hi[i]; }
      bg[ks] = bh;
    }
    f32x4 acc[8];
    #pragma unroll
    for (int mt=0;mt<8;mt++) acc[mt] = zero4;
    #pragma unroll
    for (int ks=0;ks<4;ks++){
      #pragma unroll
      for (int mt=0;mt<8;mt++) acc[mt] = MFMA16(wv[(mt*4+ks)*64 + lane], bg[ks], acc[mt]);
    }
    #pragma unroll
    for (int ks=0;ks<4;ks++){
      *(f32x4*)(xw + n15*132 + ks*32 + quad*8)     = xl[ks];
      *(f32x4*)(xw + n15*132 + ks*32 + quad*8 + 4) = xh[ks];
    }
    LGKM_WAIT;
    {
      float* gx = x + (size_t)a0*128;
      #pragma unroll
      for (int it=0;it<8;it++){
        int off = it*256 + lane*4;
        f32x4 v = *(const f32x4*)(xw + (off>>7)*132 + (off&127));
        *(f32x4*)(gx + off) = v;
      }
    }
    LGKM_WAIT;
    #pragma unroll
    for (int mt=0;mt<8;mt++){
      union { ushort_t s[4]; uint2 v; } pk;
      #pragma unroll
      for (int r=0;r<4;r++) pk.s[r] = f2h(acc[mt][r]);
      *(uint2*)(sw + n15*132 + mt*16 + quad*4) = pk.v;
    }
    LGKM_WAIT;
    {
      ushort_t* gh = h + (size_t)a0*128;
      #pragma unroll
      for (int it=0;it<4;it++){
        int off = it*512 + lane*8;
        uint4 v = *(const uint4*)(sw + (off>>7)*132 + (off&127));
        *(uint4*)(gh + off) = v;
      }
    }
    LGKM_WAIT;
  }
}

// ---------------- mega message pass + fused node update (r15, 611us proven) ---
__global__ __launch_bounds__(256,3) void mega_pass(
  const uint4* __restrict__ meta, const ushort_t* __restrict__ hin,
  ushort_t* __restrict__ hout,
  const ushort_t* __restrict__ w1g, const ushort_t* __restrict__ w2g,
  const float* __restrict__ b2,
  const ushort_t* __restrict__ l2T, const ushort_t* __restrict__ bkT,
  const ushort_t* __restrict__ l1Tn,
  const float* __restrict__ l2b, const float* __restrict__ bb,
  const int* __restrict__ segend, int first_atom,
  ushort_t* __restrict__ W, float* __restrict__ x, int do_h)
{
  __shared__ ushort_t ldsW2[16384];     // 32 KB: w2T A-frags
  __shared__ ushort_t st[4*2112];       // 16.5 KB: per-wave transpose buffers
  ushort_t* nt = st;                    // node tile aliases wave-0 region
  const int wave = threadIdx.x>>6, lane = threadIdx.x&63;
  const int quad = lane>>4, n15 = lane&15;
  {
    const uint4* s2 = (const uint4*)w2g; uint4* d2 = (uint4*)ldsW2;
    #pragma unroll
    for (int i=0;i<8;i++) d2[threadIdx.x + i*256] = s2[threadIdx.x + i*256];
  }
  half8 a1[16];
  const half8* w1v = (const half8*)w1g;
  #pragma unroll
  for (int i=0;i<16;i++) a1[i] = w1v[i*64 + lane];
  f32x4 b2v[8];
  #pragma unroll
  for (int mt=0;mt<8;mt++) b2v[mt] = *(const f32x4*)(b2 + mt*16 + quad*4);

  const int base  = first_atom + blockIdx.x*ATB;
  const int elo   = (base==0) ? 0 : segend[base-1];
  const int ehi   = segend[base + ATB - 1];
  const int elo_c = (first_atom==0) ? 0 : segend[first_atom-1];
  __syncthreads();

  const half8* w2l = (const half8*)ldsW2;
  ushort_t* tw = st + wave*2112;
  const f32x4 zero4 = {0.f,0.f,0.f,0.f};
  const float dd = 10.f/49.f;
  const float coefl2 = (-0.5f/(dd*dd)) * 1.4426950408889634f;

  // ---- phase 1: compute W for this block's tiles ----
  const int tlo = elo >> 4, thi = (ehi + 15) >> 4;
  for (int tile = tlo + wave; tile < thi; tile += 4){
    const int e0 = tile*16;
    uint2 dc = *(const uint2*)(meta + e0 + n15);
    float de = __uint_as_float(dc.x);
    float Cv = __uint_as_float(dc.y);
    half8 rb0, rb1;
    #pragma unroll
    for (int j=0;j<8;j++){
      int k0 = quad*8 + j;
      float t0 = de - (float)k0*dd;
      rb0[j] = (_Float16)__builtin_amdgcn_exp2f(coefl2*t0*t0);
      int k1 = 32 + quad*8 + j;
      float v1;
      if (k1 < 50){ float t1 = de - (float)k1*dd; v1 = __builtin_amdgcn_exp2f(coefl2*t1*t1); }
      else v1 = (k1 == 50) ? 1.f : 0.f;
      rb1[j] = (_Float16)v1;
    }
    // GEMM1: D[m=f1][n=e]
    f32x4 acc1[8];
    #pragma unroll
    for (int mt=0;mt<8;mt++){
      acc1[mt] = MFMA16(a1[mt*2],   rb0, zero4);
      acc1[mt] = MFMA16(a1[mt*2+1], rb1, acc1[mt]);
    }
    #pragma unroll
    for (int mt=0;mt<8;mt++){
      union { ushort_t s[4]; uint2 v; } pk;
      #pragma unroll
      for (int r=0;r<4;r++) pk.s[r] = f2h(fast_tanh(acc1[mt][r]));
      *(uint2*)(tw + n15*132 + mt*16 + quad*4) = pk.v;
    }
    LGKM_WAIT;
    // GEMM2: A = w2T frags (LDS), B = t (LDS): D[m=f2][n=e]
    f32x4 acc2[8];
    #pragma unroll
    for (int mt=0;mt<8;mt++) acc2[mt] = zero4;
    #pragma unroll
    for (int ks=0;ks<4;ks++){
      const ushort_t* ra = tw + n15*132 + ks*32 + quad*8;
      union { uint2 v[2]; half8 h16; } cc;
      cc.v[0] = *(const uint2*)(ra);
      cc.v[1] = *(const uint2*)(ra + 4);
      half8 tb = cc.h16;
      #pragma unroll
      for (int mt=0;mt<8;mt++) acc2[mt] = MFMA16(w2l[(mt*4+ks)*64 + lane], tb, acc2[mt]);
    }
    LGKM_WAIT;
    #pragma unroll
    for (int mt=0;mt<8;mt++){
      f32x4 v = acc2[mt] + b2v[mt];
      union { ushort_t s[4]; uint2 q; } pk;
      #pragma unroll
      for (int r=0;r<4;r++) pk.s[r] = f2h(v[r] * Cv);
      *(uint2*)(tw + n15*132 + mt*16 + quad*4) = pk.q;
    }
    LGKM_WAIT;
    #pragma unroll
    for (int it=0;it<4;it++){
      int off = it*512 + lane*8;
      int erow = e0 + (off>>7);
      if (erow >= elo_c){
        uint4 v = *(const uint4*)(tw + (off>>7)*132 + (off&127));
        *(uint4*)(W + (size_t)(erow - elo_c)*128 + (off&127)) = v;
      }
    }
  }
  __threadfence_block();
  __syncthreads();

  // ---- phase 2: gather-multiply-reduce -> fp16 agg tile in LDS ----
  {
    const int g  = threadIdx.x >> 4;
    const int tf = threadIdx.x & 15;
    const int a  = base + g;
    const int lo = (a==0) ? 0 : segend[a-1];
    const int hi = segend[a];
    float acc[8];
    #pragma unroll
    for (int j=0;j<8;j++) acc[j] = 0.f;
    const int* msrc = (const int*)meta;
    int e = lo;
    if (e < hi){
      int src = msrc[(size_t)e*4 + 2];
      half8 wv = *(const half8*)(W + (size_t)(e - elo_c)*128 + tf*8);
      half8 hv = *(const half8*)(hin + (size_t)src*128 + tf*8);
      while (true){
        int en = e + 1;
        bool more = en < hi;
        half8 wv2 = wv, hv2 = hv;
        if (more){
          int sn = msrc[(size_t)en*4 + 2];
          wv2 = *(const half8*)(W + (size_t)(en - elo_c)*128 + tf*8);
          hv2 = *(const half8*)(hin + (size_t)sn*128 + tf*8);
        }
        #pragma unroll
        for (int j=0;j<8;j++) acc[j] += (float)wv[j] * (float)hv[j];
        if (!more) break;
        wv = wv2; hv = hv2; e = en;
      }
    }
    union { ushort_t s[8]; uint4 q; } pk;
    #pragma unroll
    for (int j=0;j<8;j++) pk.s[j] = f2h(acc[j]);
    *(uint4*)(nt + g*132 + tf*8) = pk.q;
  }
  __syncthreads();

  // ---- phase 3: node update for this block's 16-atom tile ----
  {
    half8 bg[4];
    #pragma unroll
    for (int ks=0;ks<4;ks++){
      const ushort_t* ra = nt + n15*132 + ks*32 + quad*8;
      union { uint2 v[2]; half8 h16; } cc;
      cc.v[0] = *(const uint2*)(ra);
      cc.v[1] = *(const uint2*)(ra + 4);
      bg[ks] = cc.h16;
    }
    __syncthreads();                     // all reads done before t overwrites nt
    const half8* wAv = (const half8*)l2T;
    f32x4 accA[2];
    #pragma unroll
    for (int i=0;i<2;i++) accA[i] = zero4;
    #pragma unroll
    for (int ks=0;ks<4;ks++){
      #pragma unroll
      for (int i=0;i<2;i++)
        accA[i] = MFMA16(wAv[((wave*2+i)*4+ks)*64 + lane], bg[ks], accA[i]);
    }
    #pragma unroll
    for (int i=0;i<2;i++){
      int mt = wave*2 + i;
      f32x4 bv = *(const f32x4*)(l2b + mt*16 + quad*4);
      union { ushort_t s[4]; uint2 v; } pk;
      #pragma unroll
      for (int r=0;r<4;r++) pk.s[r] = f2h(fast_tanh(accA[i][r] + bv[r]));
      *(uint2*)(nt + n15*132 + mt*16 + quad*4) = pk.v;
    }
    __syncthreads();
    half8 bg2[4];
    #pragma unroll
    for (int ks=0;ks<4;ks++){
      const ushort_t* ra = nt + n15*132 + ks*32 + quad*8;
      union { uint2 v[2]; half8 h16; } cc;
      cc.v[0] = *(const uint2*)(ra);
      cc.v[1] = *(const uint2*)(ra + 4);
      bg2[ks] = cc.h16;
    }
    __syncthreads();                     // reads done before xn16 overwrites nt
    const half8* wBv = (const half8*)bkT;
    f32x4 accB[2];
    #pragma unroll
    for (int i=0;i<2;i++) accB[i] = zero4;
    #pragma unroll
    for (int ks=0;ks<4;ks++){
      #pragma unroll
      for (int i=0;i<2;i++)
        accB[i] = MFMA16(wBv[((wave*2+i)*4+ks)*64 + lane], bg2[ks], accB[i]);
    }
    f32x4 xn[2];
    float* xp = x + (size_t)(base + n15)*128;
    #pragma unroll
    for (int i=0;i<2;i++){
      int mt = wave*2 + i;
      f32x4 bv = *(const f32x4*)(bb + mt*16 + quad*4);
      f32x4 xv = *(const f32x4*)(xp + mt*16 + quad*4);
      xn[i] = xv + accB[i] + bv;
      *(f32x4*)(xp + mt*16 + quad*4) = xn[i];
    }
    if (do_h){
      #pragma unroll
      for (int i=0;i<2;i++){
        int mt = wave*2 + i;
        union { ushort_t s[4]; uint2 v; } pk;
        #pragma unroll
        for (int r=0;r<4;r++) pk.s[r] = f2h(xn[i][r]);
        *(uint2*)(nt + n15*132 + mt*16 + quad*4) = pk.v;
      }
      __syncthreads();
      half8 bg3[4];
      #pragma unroll
      for (int ks=0;ks<4;ks++){
        const ushort_t* ra = nt + n15*132 + ks*32 + quad*8;
        union { uint2 v[2]; half8 h16; } cc;
        cc.v[0] = *(const uint2*)(ra);
        cc.v[1] = *(const uint2*)(ra + 4);
        bg3[ks] = cc.h16;
      }
      const half8* wCv = (const half8*)l1Tn;
      f32x4 accC[2];
      #pragma unroll
      for (int i=0;i<2;i++) accC[i] = zero4;
      #pragma unroll
      for (int ks=0;ks<4;ks++){
        #pragma unroll
        for (int i=0;i<2;i++)
          accC[i] = MFMA16(wCv[((wave*2+i)*4+ks)*64 + lane], bg3[ks], accC[i]);
      }
      ushort_t* hp = hout + (size_t)(base + n15)*128;
      #pragma unroll
      for (int i=0;i<2;i++){
        int mt = wave*2 + i;
        union { ushort_t s[4]; uint2 v; } pk;
        #pragma unroll
        for (int r=0;r<4;r++) pk.s[r] = f2h(accC[i][r]);
        *(uint2*)(hp + mt*16 + quad*4) = pk.v;
      }
    }
  }
}

// ---------------- fused output head: tanh(x@ow1+b1)@ow2 + ob2, per-mol sum ----
__global__ __launch_bounds__(256) void out_head(
  const float* __restrict__ x, const ushort_t* __restrict__ o1T,
  const float* __restrict__ ob1, const float* __restrict__ ow2,
  const float* __restrict__ ob2, const int* __restrict__ batch,
  float* __restrict__ out)
{
  __shared__ float part[NEXM];
  const int tid = threadIdx.x;
  if (tid < NEXM) part[tid] = 0.f;
  __syncthreads();
  const int wave = tid>>6, lane = tid&63;
  const int quad = lane>>4, n15 = lane&15;
  const half8* wv = (const half8*)o1T;
  const f32x4 zero4 = {0.f,0.f,0.f,0.f};
  f32x4 ow2v[4], ob1v[4];
  #pragma unroll
  for (int mt=0;mt<4;mt++){
    ow2v[mt] = *(const f32x4*)(ow2 + mt*16 + quad*4);
    ob1v[mt] = *(const f32x4*)(ob1 + mt*16 + quad*4);
  }
  const float ob2v = ob2[0];
  const int ntiles = NN/16;
  const int stride = gridDim.x*4;
  for (int tile = blockIdx.x*4 + wave; tile < ntiles; tile += stride){
    int a0 = tile*16;
    half8 bg[4];
    const f32x4* av = (const f32x4*)(x + (size_t)(a0 + n15)*128);
    #pragma unroll
    for (int ks=0;ks<4;ks++){
      f32x4 lo = av[ks*8 + quad*2];
      f32x4 hi = av[ks*8 + quad*2 + 1];
      half8 bh;
      #pragma unroll
      for (int i=0;i<4;i++){ bh[i]=(_Float16)lo[i]; bh[4+i]=(_Float16)hi[i]; }
      bg[ks] = bh;
    }
    f32x4 acc[4];
    #pragma unroll
    for (int mt=0;mt<4;mt++) acc[mt] = zero4;
    #pragma unroll
    for (int ks=0;ks<4;ks++){
      #pragma unroll
      for (int mt=0;mt<4;mt++) acc[mt] = MFMA16(wv[(mt*4+ks)*64 + lane], bg[ks], acc[mt]);
    }
    float e = 0.f;
    #pragma unroll
    for (int mt=0;mt<4;mt++){
      f32x4 v = acc[mt] + ob1v[mt];
      #pragma unroll
      for (int r=0;r<4;r++) e += fast_tanh(v[r]) * ow2v[mt][r];
    }
    e += __shfl_xor(e, 16, 64);
    e += __shfl_xor(e, 32, 64);
    if (quad == 0){
      int a = a0 + n15;
      LDS_ADD(&part[batch[a]], e + ob2v);
    }
  }
  __syncthreads();
  if (tid < NEXM)
    __hip_atomic_fetch_add(out + tid, part[tid], __ATOMIC_RELAXED, __HIP_MEMORY_SCOPE_AGENT);
}

// ---------------- host orchestration ------------------------------------------
extern "C" void kernel_launch(void* const* d_in, const int* in_sizes, int n_in,
                              void* d_out, int out_size, void* d_ws, size_t ws_size,
                              hipStream_t stream)
{
  const float* pos  = (const float*)d_in[0];
  const int*   atyp = (const int*)  d_in[1];
  const int*   ei   = (const int*)  d_in[2];
  const int*   bat  = (const int*)  d_in[3];
  const float* emb  = (const float*)d_in[4];
  const float* fw1  = (const float*)d_in[5];
  const float* fb1  = (const float*)d_in[6];
  const float* fw2  = (const float*)d_in[7];
  const float* fb2  = (const float*)d_in[8];
  const float* l1w  = (const float*)d_in[9];
  const float* l2w  = (const float*)d_in[10];
  const float* l2b  = (const float*)d_in[11];
  const float* bw   = (const float*)d_in[12];
  const float* bb   = (const float*)d_in[13];
  const float* ow1  = (const float*)d_in[14];
  const float* ob1  = (const float*)d_in[15];
  const float* ow2  = (const float*)d_in[16];
  const float* ob2  = (const float*)d_in[17];
  float* out = (float*)d_out;

  char* p = (char*)d_ws;
  uint4*    meta = (uint4*)p;    p += (size_t)EE*16;     //  7.68 MB {d,C,src,dst}
  ushort_t* hA   = (ushort_t*)p; p += (size_t)NN*128*2;  //  7.68 MB
  ushort_t* hB   = (ushort_t*)p; p += (size_t)NN*128*2;  //  7.68 MB
  float*    x    = (float*)p;    p += (size_t)NN*128*4;  // 15.36 MB
  ushort_t* frags = (ushort_t*)p; p += 229376*2;         //  0.46 MB
  int*      segend = (int*)p;    p += (size_t)NN*4;      //  0.12 MB
  int*      bsum  = (int*)p;     p += 512;               //  tiny
  ushort_t* Wbuf = (ushort_t*)p; p += (size_t)WCAP_TILES*2048*2; // 43.4 MB => ~82.4 MB

  // aliased scratch: cnt lives in x (dead before embed_h0 writes x)
  int* cnt = (int*)x;

  ushort_t* w1T = frags;                 // 3 x 8192
  ushort_t* w2T = frags + 24576;         // 3 x 16384 (A-frags of w2^T)
  ushort_t* l2T = frags + 73728;         // 3 x 16384
  ushort_t* bkT = frags + 122880;        // 3 x 16384
  ushort_t* l1T = frags + 172032;        // 3 x 16384
  ushort_t* o1T = frags + 221184;        // 8192

  hipMemsetAsync(d_out, 0, NEXM*sizeof(float), stream);
  hipMemsetAsync(cnt, 0, NN*sizeof(int), stream);
  prep_weights<<<896,256,0,stream>>>(fw1,fb1,fw2,l1w,l2w,bw,ow1,frags);
  count_k<<<EE/256,256,0,stream>>>(ei, cnt);
  scan1<<<NSB,256,0,stream>>>(cnt, segend, bsum);
  scan2<<<1,128,0,stream>>>(bsum);
  scan3<<<NSB,256,0,stream>>>(segend, bsum);
  scatter_meta<<<EE/256,256,0,stream>>>(pos, ei, segend, meta); // segend -> ends
  embed_h0<<<512,256,0,stream>>>(atyp, emb, l1T, x, hA);        // x + h0 fused

  const int MBLK = CATOMS / ATB;   // 625 blocks per chunk (r15-proven config)
  for (int b=0;b<3;b++){
    const ushort_t* hin = (b & 1) ? hB : hA;
    ushort_t*       hoB = (b & 1) ? hA : hB;
    int do_h = (b < 2) ? 1 : 0;
    for (int c=0;c<3;c++){
      mega_pass<<<MBLK,256,0,stream>>>(meta, hin, hoB,
                                       w1T + b*8192, w2T + b*16384, fb2 + b*128,
                                       l2T + b*16384, bkT + b*16384,
                                       l1T + ((b<2)?(b+1):0)*16384,
                                       l2b + b*128, bb + b*128,
                                       segend, c*CATOMS, Wbuf, x, do_h);
    }
  }
  out_head<<<256,256,0,stream>>>(x, o1T, ob1, ow2, ob2, bat, out);
}